// Round 6
// baseline (584.308 us; speedup 1.0000x reference)
//
#include <hip/hip_runtime.h>
#include <hip/hip_bf16.h>
#include <stdint.h>

// ---------- types ----------
typedef __attribute__((ext_vector_type(4)))  float  f32x4;
typedef __attribute__((ext_vector_type(16))) float  f32x16;
typedef __attribute__((ext_vector_type(4)))  float  fvec4;
typedef __attribute__((ext_vector_type(8)))  short  bhalf8;   // 8 bf16 (raw bits)
typedef __attribute__((ext_vector_type(4)))  short  bhalf4;

typedef const __attribute__((address_space(1))) void glb_void;
typedef __attribute__((address_space(3))) void lds_void;

#define HD 8192
#define KDIM 1024

__device__ __forceinline__ float bf2f(short s) {
  union { float f; uint32_t u; } cv; cv.u = ((uint32_t)(uint16_t)s) << 16; return cv.f;
}
__device__ __forceinline__ short f2bf(float f) {
  union { float f; uint32_t u; } cv; cv.f = f;
  uint32_t u = cv.u;
  uint32_t r = (u + 0x7FFFu + ((u >> 16) & 1u)) >> 16;  // RNE
  return (short)(uint16_t)r;
}

// ---------- 1) f32 -> bf16 convert ----------
__global__ void cvt_f32_bf16(const float* __restrict__ in, short* __restrict__ out, int n8) {
  int idx = blockIdx.x * blockDim.x + threadIdx.x;
  if (idx >= n8) return;
  fvec4 a = ((const fvec4*)in)[idx * 2 + 0];
  fvec4 b = ((const fvec4*)in)[idx * 2 + 1];
  bhalf8 o;
  o[0]=f2bf(a[0]); o[1]=f2bf(a[1]); o[2]=f2bf(a[2]); o[3]=f2bf(a[3]);
  o[4]=f2bf(b[0]); o[5]=f2bf(b[1]); o[6]=f2bf(b[2]); o[7]=f2bf(b[3]);
  ((bhalf8*)out)[idx] = o;
}

// ---------- 2) W[1024][8192] f32 -> WT[8192][1024] bf16 ----------
__global__ __launch_bounds__(256)
void transpose_w(const float* __restrict__ W, short* __restrict__ WT) {
  __shared__ float tile[64][65];
  const int bk = blockIdx.x;   // 16
  const int bn = blockIdx.y;   // 128
  const int t  = threadIdx.x;
  #pragma unroll
  for (int p = 0; p < 4; ++p) {
    int r = p * 16 + (t >> 4);
    int c = (t & 15) * 4;
    fvec4 v = *(const fvec4*)(W + (size_t)(bk * 64 + r) * HD + bn * 64 + c);
    tile[r][c+0] = v[0]; tile[r][c+1] = v[1]; tile[r][c+2] = v[2]; tile[r][c+3] = v[3];
  }
  __syncthreads();
  #pragma unroll
  for (int p = 0; p < 2; ++p) {
    int rr = p * 32 + (t >> 3);
    int cc = (t & 7) * 8;
    bhalf8 o;
    #pragma unroll
    for (int e = 0; e < 8; ++e) o[e] = f2bf(tile[cc + e][rr]);
    *(bhalf8*)(WT + (size_t)(bn * 64 + rr) * KDIM + bk * 64 + cc) = o;
  }
}

// ---------- 3) 128x128 GEMM, 32x32x16 MFMA ----------
// A:[M][1024] bf16, BT:[8192][1024] bf16.
// TRANSPOSED: CT[b_l][n][i] (b_l = m/1024, i = m%1024); else C[m][8192].
// Per wave 64x64 = 2x2 tiles of 32x32. A/B frag: row/col = lane&31,
// k = 8*(lane>>5)+e. C/D: col=lane&31, row=(reg&3)+8*(reg>>2)+4*(lane>>5).
template <bool TRANSPOSED>
__global__ __launch_bounds__(256, 2)
void gemm_proj(const short* __restrict__ A, const short* __restrict__ BT,
               const float* __restrict__ bias, short* __restrict__ C) {
  constexpr int LDC = 136;                 // bf16 elems; 272B row stride
  __shared__ alignas(16) short smem2[128 * LDC];   // 34816 B: As+Bs, then Cs
  short* As = smem2;
  short* Bs = smem2 + 8192;
  short* Cs = smem2;

  const int t    = threadIdx.x;
  const int lane = t & 63;
  const int wave = t >> 6;
  const int bm   = blockIdx.x >> 6;
  const int bn   = blockIdx.x & 63;
  const int wr   = wave >> 1, wc = wave & 1;
  const int kb   = lane >> 5;              // k-half select (0/1)

  f32x16 acc2[2][2];
  #pragma unroll
  for (int i = 0; i < 2; ++i)
    #pragma unroll
    for (int j = 0; j < 2; ++j) acc2[i][j] = (f32x16)(0.f);

  // staging: lane covers row (c*8 + lane>>3), LDS slot (lane&7); global slot
  // pre-swizzled: gslot = (lane&7) ^ (row&7)   [rule #21: linear LDS dest]
  const int gslot = ((lane & 7) ^ (lane >> 3)) * 8;
  const short* aRow = A  + (size_t)(bm * 128 + (lane >> 3)) * KDIM + gslot;
  const short* bRow = BT + (size_t)(bn * 128 + (lane >> 3)) * KDIM + gslot;

  const int arow = wr * 64 + (lane & 31);
  const int brow = wc * 64 + (lane & 31);

  for (int kt = 0; kt < 16; ++kt) {
    __syncthreads();
    #pragma unroll
    for (int s = 0; s < 4; ++s) {
      int c = s * 4 + wave;
      __builtin_amdgcn_global_load_lds(
          (glb_void*)(aRow + (size_t)(c * 8) * KDIM + kt * 64),
          (lds_void*)((char*)As + c * 1024), 16, 0, 0);
      __builtin_amdgcn_global_load_lds(
          (glb_void*)(bRow + (size_t)(c * 8) * KDIM + kt * 64),
          (lds_void*)((char*)Bs + c * 1024), 16, 0, 0);
    }
    __syncthreads();
    #pragma unroll
    for (int ks = 0; ks < 4; ++ks) {       // K=16 per step
      bhalf8 af[2], bfm[2];
      #pragma unroll
      for (int ti = 0; ti < 2; ++ti) {
        int ra = arow + ti * 32;
        af[ti]  = *(const bhalf8*)(As + ra * 64 + (((ks * 2 + kb) ^ (ra & 7)) * 8));
        int rb = brow + ti * 32;
        bfm[ti] = *(const bhalf8*)(Bs + rb * 64 + (((ks * 2 + kb) ^ (rb & 7)) * 8));
      }
      #pragma unroll
      for (int ti = 0; ti < 2; ++ti)
        #pragma unroll
        for (int tj = 0; tj < 2; ++tj)
          acc2[ti][tj] = __builtin_amdgcn_mfma_f32_32x32x16_bf16(
              af[ti], bfm[tj], acc2[ti][tj], 0, 0, 0);
    }
  }

  __syncthreads();   // all frag reads done; reuse smem as Cs

  float bvv[2];
  #pragma unroll
  for (int tj = 0; tj < 2; ++tj)
    bvv[tj] = bias[bn * 128 + wc * 64 + tj * 32 + (lane & 31)];

  #pragma unroll
  for (int ti = 0; ti < 2; ++ti) {
    #pragma unroll
    for (int tj = 0; tj < 2; ++tj) {
      const int nloc = wc * 64 + tj * 32 + (lane & 31);
      const int mb   = wr * 64 + ti * 32 + 4 * kb;
      if (TRANSPOSED) {
        #pragma unroll
        for (int g = 0; g < 4; ++g) {
          bhalf4 pk;
          #pragma unroll
          for (int e = 0; e < 4; ++e) pk[e] = f2bf(acc2[ti][tj][g * 4 + e] + bvv[tj]);
          *(bhalf4*)(Cs + nloc * LDC + mb + 8 * g) = pk;   // Cs[n_local][m_local]
        }
      } else {
        #pragma unroll
        for (int g = 0; g < 4; ++g)
          #pragma unroll
          for (int e = 0; e < 4; ++e)
            Cs[(mb + 8 * g + e) * LDC + nloc] = f2bf(acc2[ti][tj][g * 4 + e] + bvv[tj]);
      }
    }
  }
  __syncthreads();

  #pragma unroll
  for (int p = 0; p < 8; ++p) {
    const int row = p * 16 + (t >> 4);
    const int ck  = (t & 15) * 8;
    bhalf8 v = *(const bhalf8*)(Cs + row * LDC + ck);
    if (TRANSPOSED) {
      const int n_g   = bn * 128 + row;
      const int mbase = bm * 128;
      const int bl    = mbase >> 10;                  // chunk-local batch
      const int ib    = (mbase & 1023) + ck;
      *(bhalf8*)(C + ((size_t)bl * HD + n_g) * 1024 + ib) = v;
    } else {
      const int m_g = bm * 128 + row;
      *(bhalf8*)(C + (size_t)m_g * HD + bn * 128 + ck) = v;
    }
  }
}

// ---------- 4) fused kv / softmax(axis=i) / pooled, per chunk ----------
__global__ __launch_bounds__(256)
void pool_softmax(const short* __restrict__ QT, const short* __restrict__ KT,
                  const short* __restrict__ V, float* __restrict__ pooled, int b0) {
  const int t    = threadIdx.x;
  const int lane = t & 63;
  const int wave = t >> 6;
  const int task = blockIdx.x * 4 + wave;
  const int j  = task & 1023;
  const int bh = task >> 10;
  const int bl = bh >> 3, h = bh & 7;
  const size_t n = (size_t)h * 1024 + j;

  const bhalf8* qp = (const bhalf8*)(QT + ((size_t)bl * HD + n) * 1024);
  const bhalf8* kp = (const bhalf8*)(KT + ((size_t)bl * HD + n) * 1024);
  const bhalf8* vp = (const bhalf8*)(V + ((size_t)bl * 1024 + j) * HD + (size_t)h * 1024);

  bhalf8 q0 = qp[lane], q1 = qp[64 + lane];
  bhalf8 k0 = kp[lane], k1 = kp[64 + lane];
  bhalf8 v0 = vp[lane], v1 = vp[64 + lane];

  float q[16], x[16];
  float m = -1e30f;
  #pragma unroll
  for (int e = 0; e < 8; ++e) {
    q[e]     = bf2f(q0[e]);  q[8 + e] = bf2f(q1[e]);
    x[e]     = bf2f(k0[e]) * bf2f(v0[e]) * 0.03125f;
    x[8 + e] = bf2f(k1[e]) * bf2f(v1[e]) * 0.03125f;
  }
  #pragma unroll
  for (int e = 0; e < 16; ++e) m = fmaxf(m, x[e]);
  #pragma unroll
  for (int off = 32; off; off >>= 1) m = fmaxf(m, __shfl_xor(m, off, 64));
  float se = 0.f, sq = 0.f;
  #pragma unroll
  for (int e = 0; e < 16; ++e) { float ex = __expf(x[e] - m); se += ex; sq += ex * q[e]; }
  #pragma unroll
  for (int off = 32; off; off >>= 1) { se += __shfl_xor(se, off, 64); sq += __shfl_xor(sq, off, 64); }
  if (lane == 0) pooled[((size_t)(b0 * 8) + bh) * 1024 + j] = sq / se;
}

// ---------- 5) out = pooled @ WL + bL, k-split x4 + reduce ----------
__global__ __launch_bounds__(256)
void final_gemm2(const float* __restrict__ pooled, const float* __restrict__ WL,
                 float* __restrict__ part) {
  __shared__ float sp[256][8];
  const int t  = threadIdx.x;
  const int bn = blockIdx.x;   // 32
  const int mg = blockIdx.y;   // 8
  const int kc = blockIdx.z;   // 4
  for (int idx = t; idx < 2048; idx += 256) {
    int mm = idx >> 8, k = idx & 255;
    sp[k][mm] = pooled[(size_t)(mg * 8 + mm) * 1024 + kc * 256 + k];
  }
  __syncthreads();
  const int n = bn * 256 + t;
  float acc[8];
  #pragma unroll
  for (int mm = 0; mm < 8; ++mm) acc[mm] = 0.f;
  const float* wp = WL + (size_t)(kc * 256) * HD + n;
  #pragma unroll 1
  for (int k0 = 0; k0 < 256; k0 += 8) {
    float wv[8];
    #pragma unroll
    for (int u = 0; u < 8; ++u) wv[u] = wp[(size_t)(k0 + u) * HD];
    #pragma unroll
    for (int u = 0; u < 8; ++u)
      #pragma unroll
      for (int mm = 0; mm < 8; ++mm) acc[mm] = fmaf(sp[k0 + u][mm], wv[u], acc[mm]);
  }
  #pragma unroll
  for (int mm = 0; mm < 8; ++mm)
    part[((size_t)kc * 64 + mg * 8 + mm) * HD + n] = acc[mm];
}

__global__ __launch_bounds__(256)
void final_reduce(const float* __restrict__ part, const float* __restrict__ bL,
                  float* __restrict__ out) {
  int id = blockIdx.x * 256 + threadIdx.x;        // 131072 f32x4 groups
  const f32x4* p4 = (const f32x4*)part;
  f32x4 s = p4[id];
  s = s + p4[131072 + id];
  s = s + p4[262144 + id];
  s = s + p4[393216 + id];
  f32x4 bb = ((const f32x4*)bL)[id & 2047];
  ((f32x4*)out)[id] = s + bb;
}

// ---------- launch ----------
extern "C" void kernel_launch(void* const* d_in, const int* in_sizes, int n_in,
                              void* d_out, int out_size, void* d_ws, size_t ws_size,
                              hipStream_t stream) {
  const float* inputs = (const float*)d_in[0];
  const float* Wq = (const float*)d_in[1];
  const float* bq = (const float*)d_in[2];
  const float* Wk = (const float*)d_in[3];
  const float* bk = (const float*)d_in[4];
  const float* Wv = (const float*)d_in[5];
  const float* bv = (const float*)d_in[6];
  const float* WL = (const float*)d_in[7];
  const float* bL = (const float*)d_in[8];
  float* out = (float*)d_out;

  const size_t MB = 1ull << 20;
  int CB; bool threeW;
  if      (ws_size >= 449 * MB) { CB = 8; threeW = true;  }
  else if (ws_size >= 249 * MB) { CB = 4; threeW = true;  }
  else if (ws_size >= 149 * MB) { CB = 2; threeW = true;  }
  else if (ws_size >=  99 * MB) { CB = 1; threeW = true;  }
  else                          { CB = 1; threeW = false; }

  char* ws = (char*)d_ws;
  short* WT0 = (short*)ws;
  short* WT1 = threeW ? (short*)(ws + 16 * MB) : WT0;
  short* WT2 = threeW ? (short*)(ws + 32 * MB) : WT0;
  char* pp = ws + (threeW ? 48 : 16) * MB;
  short* Abf = (short*)pp;  pp += (size_t)CB * 2  * MB;
  short* QT  = (short*)pp;  pp += (size_t)CB * 16 * MB;
  short* KT  = (short*)pp;  pp += (size_t)CB * 16 * MB;
  short* Vn  = (short*)pp;  pp += (size_t)CB * 16 * MB;
  float* pooled = (float*)pp;
  float* part = (float*)QT;      // 8 MB partials; QT free when final runs

  const float* Wmat[3] = {Wq, Wk, Wv};
  const float* bvec[3] = {bq, bk, bv};
  short*       WTs[3]  = {WT0, WT1, WT2};
  short*       Cout[3] = {QT, KT, Vn};

  dim3 tg(16, 128);
  if (threeW)
    for (int pj = 0; pj < 3; ++pj)
      transpose_w<<<tg, 256, 0, stream>>>(Wmat[pj], WTs[pj]);

  for (int b0 = 0; b0 < 8; b0 += CB) {
    cvt_f32_bf16<<<CB * 512, 256, 0, stream>>>(inputs + ((size_t)b0 << 20), Abf, CB << 17);
    for (int pj = 0; pj < 3; ++pj) {
      if (!threeW)
        transpose_w<<<tg, 256, 0, stream>>>(Wmat[pj], WT0);
      if (pj < 2)
        gemm_proj<true ><<<CB * 512, 256, 0, stream>>>(Abf, WTs[pj], bvec[pj], Cout[pj]);
      else
        gemm_proj<false><<<CB * 512, 256, 0, stream>>>(Abf, WTs[pj], bvec[pj], Cout[pj]);
    }
    pool_softmax<<<CB * 2048, 256, 0, stream>>>(QT, KT, Vn, pooled, b0);
  }
  final_gemm2<<<dim3(32, 8, 4), 256, 0, stream>>>(pooled, WL, part);
  final_reduce<<<512, 256, 0, stream>>>(part, bL, out);
}

// Round 7
// 574.857 us; speedup vs baseline: 1.0164x; 1.0164x over previous
//
#include <hip/hip_runtime.h>
#include <hip/hip_bf16.h>
#include <stdint.h>

// ---------- types ----------
typedef __attribute__((ext_vector_type(4))) float  f32x4;
typedef __attribute__((ext_vector_type(4))) float  fvec4;
typedef __attribute__((ext_vector_type(8))) short  bhalf8;   // 8 bf16 (raw bits)
typedef __attribute__((ext_vector_type(4))) short  bhalf4;

typedef const __attribute__((address_space(1))) void glb_void;
typedef __attribute__((address_space(3))) void lds_void;

#define HD 8192
#define KDIM 1024

__device__ __forceinline__ float bf2f(short s) {
  union { float f; uint32_t u; } cv; cv.u = ((uint32_t)(uint16_t)s) << 16; return cv.f;
}
__device__ __forceinline__ short f2bf(float f) {
  union { float f; uint32_t u; } cv; cv.f = f;
  uint32_t u = cv.u;
  uint32_t r = (u + 0x7FFFu + ((u >> 16) & 1u)) >> 16;  // RNE
  return (short)(uint16_t)r;
}

// ---------- 1) f32 -> bf16 convert ----------
__global__ void cvt_f32_bf16(const float* __restrict__ in, short* __restrict__ out, int n8) {
  int idx = blockIdx.x * blockDim.x + threadIdx.x;
  if (idx >= n8) return;
  fvec4 a = ((const fvec4*)in)[idx * 2 + 0];
  fvec4 b = ((const fvec4*)in)[idx * 2 + 1];
  bhalf8 o;
  o[0]=f2bf(a[0]); o[1]=f2bf(a[1]); o[2]=f2bf(a[2]); o[3]=f2bf(a[3]);
  o[4]=f2bf(b[0]); o[5]=f2bf(b[1]); o[6]=f2bf(b[2]); o[7]=f2bf(b[3]);
  ((bhalf8*)out)[idx] = o;
}

// ---------- 2) W[1024][8192] f32 -> WT[8192][1024] bf16 ----------
__global__ __launch_bounds__(256)
void transpose_w(const float* __restrict__ W, short* __restrict__ WT) {
  __shared__ float tile[64][65];
  const int bk = blockIdx.x;   // 16
  const int bn = blockIdx.y;   // 128
  const int t  = threadIdx.x;
  #pragma unroll
  for (int p = 0; p < 4; ++p) {
    int r = p * 16 + (t >> 4);
    int c = (t & 15) * 4;
    fvec4 v = *(const fvec4*)(W + (size_t)(bk * 64 + r) * HD + bn * 64 + c);
    tile[r][c+0] = v[0]; tile[r][c+1] = v[1]; tile[r][c+2] = v[2]; tile[r][c+3] = v[3];
  }
  __syncthreads();
  #pragma unroll
  for (int p = 0; p < 2; ++p) {
    int rr = p * 32 + (t >> 3);
    int cc = (t & 7) * 8;
    bhalf8 o;
    #pragma unroll
    for (int e = 0; e < 8; ++e) o[e] = f2bf(tile[cc + e][rr]);
    *(bhalf8*)(WT + (size_t)(bn * 64 + rr) * KDIM + bk * 64 + cc) = o;
  }
}

// ---------- 3) 128x128 GEMM, 16x16x32 MFMA (R5-verified K-loop) ----------
// A:[M][1024] bf16, BT:[8192][1024] bf16.
// TRANSPOSED: CT[b_l][n][i] (b_l = m/1024, i = m%1024) via DIRECT global
// stores (no LDS epilogue -> 32KB LDS, 5 blocks/CU); else C[m][8192] via
// LDS-transpose epilogue (34816B).
template <bool TRANSPOSED>
__global__ __launch_bounds__(256, 4)
void gemm_proj(const short* __restrict__ A, const short* __restrict__ BT,
               const float* __restrict__ bias, short* __restrict__ C) {
  constexpr int LDC = 136;                 // bf16 elems; 272B row stride
  constexpr int NSH = TRANSPOSED ? 16384 : 17408;
  __shared__ alignas(16) short smem2[NSH];
  short* As = smem2;
  short* Bs = smem2 + 8192;
  short* Cs = smem2;

  const int t    = threadIdx.x;
  const int lane = t & 63;
  const int wave = t >> 6;
  const int bm   = blockIdx.x >> 6;
  const int bn   = blockIdx.x & 63;
  const int wr   = wave >> 1, wc = wave & 1;

  f32x4 acc[4][4];
  #pragma unroll
  for (int i = 0; i < 4; ++i)
    #pragma unroll
    for (int j = 0; j < 4; ++j) acc[i][j] = (f32x4)(0.f);

  // staging: lane covers row (c*8 + lane>>3), LDS slot (lane&7); global slot
  // pre-swizzled: gslot = (lane&7) ^ (row&7)   [rule #21: linear LDS dest]
  const int gslot = ((lane & 7) ^ (lane >> 3)) * 8;
  const short* aRow = A  + (size_t)(bm * 128 + (lane >> 3)) * KDIM + gslot;
  const short* bRow = BT + (size_t)(bn * 128 + (lane >> 3)) * KDIM + gslot;

  const int arow = wr * 64 + (lane & 15);
  const int brow = wc * 64 + (lane & 15);
  const int kbase = (lane >> 4) * 8;       // pre-XOR k elem offset within row
  const int swz  = (lane & 7) * 8;         // read-side XOR (row&7 == lane&7)

  for (int kt = 0; kt < 16; ++kt) {
    __syncthreads();
    #pragma unroll
    for (int s = 0; s < 4; ++s) {
      int c = s * 4 + wave;
      __builtin_amdgcn_global_load_lds(
          (glb_void*)(aRow + (size_t)(c * 8) * KDIM + kt * 64),
          (lds_void*)((char*)As + c * 1024), 16, 0, 0);
      __builtin_amdgcn_global_load_lds(
          (glb_void*)(bRow + (size_t)(c * 8) * KDIM + kt * 64),
          (lds_void*)((char*)Bs + c * 1024), 16, 0, 0);
    }
    __syncthreads();
    #pragma unroll
    for (int kk = 0; kk < 2; ++kk) {
      bhalf8 af[4], bfm[4];
      #pragma unroll
      for (int mi = 0; mi < 4; ++mi)
        af[mi] = *(const bhalf8*)(As + (arow + mi * 16) * 64 + ((kk * 32 + kbase) ^ swz));
      #pragma unroll
      for (int ni = 0; ni < 4; ++ni)
        bfm[ni] = *(const bhalf8*)(Bs + (brow + ni * 16) * 64 + ((kk * 32 + kbase) ^ swz));
      #pragma unroll
      for (int mi = 0; mi < 4; ++mi)
        #pragma unroll
        for (int ni = 0; ni < 4; ++ni)
          acc[mi][ni] = __builtin_amdgcn_mfma_f32_16x16x32_bf16(af[mi], bfm[ni], acc[mi][ni], 0, 0, 0);
    }
  }

  float bv4[4];
  #pragma unroll
  for (int ni = 0; ni < 4; ++ni) bv4[ni] = bias[bn * 128 + wc * 64 + ni * 16 + (lane & 15)];

  if (TRANSPOSED) {
    // direct stores: CT row n_g gets 16 consecutive i's per 4-lane group
    const int bl    = bm >> 3;
    const int ibase = (bm & 7) * 128 + wr * 64 + (lane >> 4) * 4;
    #pragma unroll
    for (int ni = 0; ni < 4; ++ni) {
      const int n_g = bn * 128 + wc * 64 + ni * 16 + (lane & 15);
      short* crow = C + ((size_t)bl * HD + n_g) * 1024 + ibase;
      #pragma unroll
      for (int mi = 0; mi < 4; ++mi) {
        bhalf4 pk;
        #pragma unroll
        for (int e = 0; e < 4; ++e) pk[e] = f2bf(acc[mi][ni][e] + bv4[ni]);
        *(bhalf4*)(crow + mi * 16) = pk;
      }
    }
  } else {
    __syncthreads();   // all frag reads done; reuse smem as Cs
    #pragma unroll
    for (int mi = 0; mi < 4; ++mi) {
      #pragma unroll
      for (int ni = 0; ni < 4; ++ni) {
        const int r0 = wr * 64 + mi * 16 + (lane >> 4) * 4;   // m_local
        const int cl = wc * 64 + ni * 16 + (lane & 15);       // n_local
        #pragma unroll
        for (int e = 0; e < 4; ++e) Cs[(r0 + e) * LDC + cl] = f2bf(acc[mi][ni][e] + bv4[ni]);
      }
    }
    __syncthreads();
    #pragma unroll
    for (int p = 0; p < 8; ++p) {
      const int row = p * 16 + (t >> 4);
      const int ck  = (t & 15) * 8;
      bhalf8 v = *(const bhalf8*)(Cs + row * LDC + ck);
      const int m_g = bm * 128 + row;
      *(bhalf8*)(C + (size_t)m_g * HD + bn * 128 + ck) = v;
    }
  }
}

// ---------- 4) fused kv / softmax(axis=i) / pooled, per chunk ----------
__global__ __launch_bounds__(256)
void pool_softmax(const short* __restrict__ QT, const short* __restrict__ KT,
                  const short* __restrict__ V, float* __restrict__ pooled, int b0) {
  const int t    = threadIdx.x;
  const int lane = t & 63;
  const int wave = t >> 6;
  const int task = blockIdx.x * 4 + wave;
  const int j  = task & 1023;
  const int bh = task >> 10;
  const int bl = bh >> 3, h = bh & 7;
  const size_t n = (size_t)h * 1024 + j;

  const bhalf8* qp = (const bhalf8*)(QT + ((size_t)bl * HD + n) * 1024);
  const bhalf8* kp = (const bhalf8*)(KT + ((size_t)bl * HD + n) * 1024);
  const bhalf8* vp = (const bhalf8*)(V + ((size_t)bl * 1024 + j) * HD + (size_t)h * 1024);

  bhalf8 q0 = qp[lane], q1 = qp[64 + lane];
  bhalf8 k0 = kp[lane], k1 = kp[64 + lane];
  bhalf8 v0 = vp[lane], v1 = vp[64 + lane];

  float q[16], x[16];
  float m = -1e30f;
  #pragma unroll
  for (int e = 0; e < 8; ++e) {
    q[e]     = bf2f(q0[e]);  q[8 + e] = bf2f(q1[e]);
    x[e]     = bf2f(k0[e]) * bf2f(v0[e]) * 0.03125f;
    x[8 + e] = bf2f(k1[e]) * bf2f(v1[e]) * 0.03125f;
  }
  #pragma unroll
  for (int e = 0; e < 16; ++e) m = fmaxf(m, x[e]);
  #pragma unroll
  for (int off = 32; off; off >>= 1) m = fmaxf(m, __shfl_xor(m, off, 64));
  float se = 0.f, sq = 0.f;
  #pragma unroll
  for (int e = 0; e < 16; ++e) { float ex = __expf(x[e] - m); se += ex; sq += ex * q[e]; }
  #pragma unroll
  for (int off = 32; off; off >>= 1) { se += __shfl_xor(se, off, 64); sq += __shfl_xor(sq, off, 64); }
  if (lane == 0) pooled[((size_t)(b0 * 8) + bh) * 1024 + j] = sq / se;
}

// ---------- 5) out = pooled @ WL + bL, k-split x4 + reduce ----------
__global__ __launch_bounds__(256)
void final_gemm2(const float* __restrict__ pooled, const float* __restrict__ WL,
                 float* __restrict__ part) {
  __shared__ float sp[256][8];
  const int t  = threadIdx.x;
  const int bn = blockIdx.x;   // 32
  const int mg = blockIdx.y;   // 8
  const int kc = blockIdx.z;   // 4
  for (int idx = t; idx < 2048; idx += 256) {
    int mm = idx >> 8, k = idx & 255;
    sp[k][mm] = pooled[(size_t)(mg * 8 + mm) * 1024 + kc * 256 + k];
  }
  __syncthreads();
  const int n = bn * 256 + t;
  float acc[8];
  #pragma unroll
  for (int mm = 0; mm < 8; ++mm) acc[mm] = 0.f;
  const float* wp = WL + (size_t)(kc * 256) * HD + n;
  #pragma unroll 1
  for (int k0 = 0; k0 < 256; k0 += 8) {
    float wv[8];
    #pragma unroll
    for (int u = 0; u < 8; ++u) wv[u] = wp[(size_t)(k0 + u) * HD];
    #pragma unroll
    for (int u = 0; u < 8; ++u)
      #pragma unroll
      for (int mm = 0; mm < 8; ++mm) acc[mm] = fmaf(sp[k0 + u][mm], wv[u], acc[mm]);
  }
  #pragma unroll
  for (int mm = 0; mm < 8; ++mm)
    part[((size_t)kc * 64 + mg * 8 + mm) * HD + n] = acc[mm];
}

__global__ __launch_bounds__(256)
void final_reduce(const float* __restrict__ part, const float* __restrict__ bL,
                  float* __restrict__ out) {
  int id = blockIdx.x * 256 + threadIdx.x;        // 131072 f32x4 groups
  const f32x4* p4 = (const f32x4*)part;
  f32x4 s = p4[id];
  s = s + p4[131072 + id];
  s = s + p4[262144 + id];
  s = s + p4[393216 + id];
  f32x4 bb = ((const f32x4*)bL)[id & 2047];
  ((f32x4*)out)[id] = s + bb;
}

// ---------- launch ----------
extern "C" void kernel_launch(void* const* d_in, const int* in_sizes, int n_in,
                              void* d_out, int out_size, void* d_ws, size_t ws_size,
                              hipStream_t stream) {
  const float* inputs = (const float*)d_in[0];
  const float* Wq = (const float*)d_in[1];
  const float* bq = (const float*)d_in[2];
  const float* Wk = (const float*)d_in[3];
  const float* bk = (const float*)d_in[4];
  const float* Wv = (const float*)d_in[5];
  const float* bv = (const float*)d_in[6];
  const float* WL = (const float*)d_in[7];
  const float* bL = (const float*)d_in[8];
  float* out = (float*)d_out;

  const size_t MB = 1ull << 20;
  int CB; bool threeW;
  if      (ws_size >= 449 * MB) { CB = 8; threeW = true;  }
  else if (ws_size >= 249 * MB) { CB = 4; threeW = true;  }
  else if (ws_size >= 149 * MB) { CB = 2; threeW = true;  }
  else if (ws_size >=  99 * MB) { CB = 1; threeW = true;  }
  else                          { CB = 1; threeW = false; }

  char* ws = (char*)d_ws;
  short* WT0 = (short*)ws;
  short* WT1 = threeW ? (short*)(ws + 16 * MB) : WT0;
  short* WT2 = threeW ? (short*)(ws + 32 * MB) : WT0;
  char* pp = ws + (threeW ? 48 : 16) * MB;
  short* Abf = (short*)pp;  pp += (size_t)CB * 2  * MB;
  short* QT  = (short*)pp;  pp += (size_t)CB * 16 * MB;
  short* KT  = (short*)pp;  pp += (size_t)CB * 16 * MB;
  short* Vn  = (short*)pp;  pp += (size_t)CB * 16 * MB;
  float* pooled = (float*)pp;
  float* part = (float*)QT;      // 8 MB partials; QT free when final runs

  const float* Wmat[3] = {Wq, Wk, Wv};
  const float* bvec[3] = {bq, bk, bv};
  short*       WTs[3]  = {WT0, WT1, WT2};
  short*       Cout[3] = {QT, KT, Vn};

  dim3 tg(16, 128);
  if (threeW)
    for (int pj = 0; pj < 3; ++pj)
      transpose_w<<<tg, 256, 0, stream>>>(Wmat[pj], WTs[pj]);

  for (int b0 = 0; b0 < 8; b0 += CB) {
    cvt_f32_bf16<<<CB * 512, 256, 0, stream>>>(inputs + ((size_t)b0 << 20), Abf, CB << 17);
    for (int pj = 0; pj < 3; ++pj) {
      if (!threeW)
        transpose_w<<<tg, 256, 0, stream>>>(Wmat[pj], WT0);
      if (pj < 2)
        gemm_proj<true ><<<CB * 512, 256, 0, stream>>>(Abf, WTs[pj], bvec[pj], Cout[pj]);
      else
        gemm_proj<false><<<CB * 512, 256, 0, stream>>>(Abf, WTs[pj], bvec[pj], Cout[pj]);
    }
    pool_softmax<<<CB * 2048, 256, 0, stream>>>(QT, KT, Vn, pooled, b0);
  }
  final_gemm2<<<dim3(32, 8, 4), 256, 0, stream>>>(pooled, WL, part);
  final_reduce<<<512, 256, 0, stream>>>(part, bL, out);
}

// Round 8
// 531.626 us; speedup vs baseline: 1.0991x; 1.0813x over previous
//
#include <hip/hip_runtime.h>
#include <hip/hip_bf16.h>
#include <stdint.h>

// ---------- types ----------
typedef __attribute__((ext_vector_type(4))) float  f32x4;
typedef __attribute__((ext_vector_type(4))) float  fvec4;
typedef __attribute__((ext_vector_type(8))) short  bhalf8;   // 8 bf16 (raw bits)
typedef __attribute__((ext_vector_type(4))) short  bhalf4;

typedef const __attribute__((address_space(1))) void glb_void;
typedef __attribute__((address_space(3))) void lds_void;

#define HD 8192
#define KDIM 1024

__device__ __forceinline__ float bf2f(short s) {
  union { float f; uint32_t u; } cv; cv.u = ((uint32_t)(uint16_t)s) << 16; return cv.f;
}
__device__ __forceinline__ short f2bf(float f) {
  union { float f; uint32_t u; } cv; cv.f = f;
  uint32_t u = cv.u;
  uint32_t r = (u + 0x7FFFu + ((u >> 16) & 1u)) >> 16;  // RNE
  return (short)(uint16_t)r;
}

// ---------- 1) f32 -> bf16 convert ----------
__global__ void cvt_f32_bf16(const float* __restrict__ in, short* __restrict__ out, int n8) {
  int idx = blockIdx.x * blockDim.x + threadIdx.x;
  if (idx >= n8) return;
  fvec4 a = ((const fvec4*)in)[idx * 2 + 0];
  fvec4 b = ((const fvec4*)in)[idx * 2 + 1];
  bhalf8 o;
  o[0]=f2bf(a[0]); o[1]=f2bf(a[1]); o[2]=f2bf(a[2]); o[3]=f2bf(a[3]);
  o[4]=f2bf(b[0]); o[5]=f2bf(b[1]); o[6]=f2bf(b[2]); o[7]=f2bf(b[3]);
  ((bhalf8*)out)[idx] = o;
}

// ---------- 2) W[1024][8192] f32 -> WT[8192][1024] bf16 ----------
__global__ __launch_bounds__(256)
void transpose_w(const float* __restrict__ W, short* __restrict__ WT) {
  __shared__ float tile[64][65];
  const int bk = blockIdx.x;   // 16
  const int bn = blockIdx.y;   // 128
  const int t  = threadIdx.x;
  #pragma unroll
  for (int p = 0; p < 4; ++p) {
    int r = p * 16 + (t >> 4);
    int c = (t & 15) * 4;
    fvec4 v = *(const fvec4*)(W + (size_t)(bk * 64 + r) * HD + bn * 64 + c);
    tile[r][c+0] = v[0]; tile[r][c+1] = v[1]; tile[r][c+2] = v[2]; tile[r][c+3] = v[3];
  }
  __syncthreads();
  #pragma unroll
  for (int p = 0; p < 2; ++p) {
    int rr = p * 32 + (t >> 3);
    int cc = (t & 7) * 8;
    bhalf8 o;
    #pragma unroll
    for (int e = 0; e < 8; ++e) o[e] = f2bf(tile[cc + e][rr]);
    *(bhalf8*)(WT + (size_t)(bn * 64 + rr) * KDIM + bk * 64 + cc) = o;
  }
}

// ---------- 3) 128x128 GEMM (R5-verified best: ~1018 TF) ----------
// A:[M][1024] bf16, BT:[8192][1024] bf16.
// TRANSPOSED: CT[b_l][n][i] (b_l = m/1024, i = m%1024); else C[m][8192].
template <bool TRANSPOSED>
__global__ __launch_bounds__(256, 2)
void gemm_proj(const short* __restrict__ A, const short* __restrict__ BT,
               const float* __restrict__ bias, short* __restrict__ C) {
  constexpr int LDC = 136;                 // bf16 elems; 272B row stride
  __shared__ alignas(16) short smem2[128 * LDC];   // 34816 B: As+Bs, then Cs
  short* As = smem2;
  short* Bs = smem2 + 8192;
  short* Cs = smem2;

  const int t    = threadIdx.x;
  const int lane = t & 63;
  const int wave = t >> 6;
  const int bm   = blockIdx.x >> 6;
  const int bn   = blockIdx.x & 63;
  const int wr   = wave >> 1, wc = wave & 1;

  f32x4 acc[4][4];
  #pragma unroll
  for (int i = 0; i < 4; ++i)
    #pragma unroll
    for (int j = 0; j < 4; ++j) acc[i][j] = (f32x4)(0.f);

  // staging: lane covers row (c*8 + lane>>3), LDS slot (lane&7); global slot
  // pre-swizzled: gslot = (lane&7) ^ (row&7)   [rule #21: linear LDS dest]
  const int gslot = ((lane & 7) ^ (lane >> 3)) * 8;
  const short* aRow = A  + (size_t)(bm * 128 + (lane >> 3)) * KDIM + gslot;
  const short* bRow = BT + (size_t)(bn * 128 + (lane >> 3)) * KDIM + gslot;

  const int arow = wr * 64 + (lane & 15);
  const int brow = wc * 64 + (lane & 15);
  const int kbase = (lane >> 4) * 8;       // pre-XOR k elem offset within row
  const int swz  = (lane & 7) * 8;         // read-side XOR (row&7 == lane&7)

  for (int kt = 0; kt < 16; ++kt) {
    __syncthreads();
    #pragma unroll
    for (int s = 0; s < 4; ++s) {
      int c = s * 4 + wave;
      __builtin_amdgcn_global_load_lds(
          (glb_void*)(aRow + (size_t)(c * 8) * KDIM + kt * 64),
          (lds_void*)((char*)As + c * 1024), 16, 0, 0);
      __builtin_amdgcn_global_load_lds(
          (glb_void*)(bRow + (size_t)(c * 8) * KDIM + kt * 64),
          (lds_void*)((char*)Bs + c * 1024), 16, 0, 0);
    }
    __syncthreads();
    #pragma unroll
    for (int kk = 0; kk < 2; ++kk) {
      bhalf8 af[4], bfm[4];
      #pragma unroll
      for (int mi = 0; mi < 4; ++mi)
        af[mi] = *(const bhalf8*)(As + (arow + mi * 16) * 64 + ((kk * 32 + kbase) ^ swz));
      #pragma unroll
      for (int ni = 0; ni < 4; ++ni)
        bfm[ni] = *(const bhalf8*)(Bs + (brow + ni * 16) * 64 + ((kk * 32 + kbase) ^ swz));
      #pragma unroll
      for (int mi = 0; mi < 4; ++mi)
        #pragma unroll
        for (int ni = 0; ni < 4; ++ni)
          acc[mi][ni] = __builtin_amdgcn_mfma_f32_16x16x32_bf16(af[mi], bfm[ni], acc[mi][ni], 0, 0, 0);
    }
  }

  __syncthreads();   // all frag reads done; reuse smem as Cs

  float bv4[4];
  #pragma unroll
  for (int ni = 0; ni < 4; ++ni) bv4[ni] = bias[bn * 128 + wc * 64 + ni * 16 + (lane & 15)];

  #pragma unroll
  for (int mi = 0; mi < 4; ++mi) {
    #pragma unroll
    for (int ni = 0; ni < 4; ++ni) {
      const int r0 = wr * 64 + mi * 16 + (lane >> 4) * 4;   // m_local
      const int cl = wc * 64 + ni * 16 + (lane & 15);       // n_local
      if (TRANSPOSED) {
        bhalf4 pk;
        #pragma unroll
        for (int e = 0; e < 4; ++e) pk[e] = f2bf(acc[mi][ni][e] + bv4[ni]);
        *(bhalf4*)(Cs + cl * LDC + r0) = pk;           // Cs[n_local][m_local]
      } else {
        #pragma unroll
        for (int e = 0; e < 4; ++e) Cs[(r0 + e) * LDC + cl] = f2bf(acc[mi][ni][e] + bv4[ni]);
      }
    }
  }
  __syncthreads();

  #pragma unroll
  for (int p = 0; p < 8; ++p) {
    const int row = p * 16 + (t >> 4);
    const int ck  = (t & 15) * 8;
    bhalf8 v = *(const bhalf8*)(Cs + row * LDC + ck);
    if (TRANSPOSED) {
      const int n_g   = bn * 128 + row;
      const int mbase = bm * 128;
      const int bl    = mbase >> 10;                  // chunk-local batch
      const int ib    = (mbase & 1023) + ck;
      *(bhalf8*)(C + ((size_t)bl * HD + n_g) * 1024 + ib) = v;
    } else {
      const int m_g = bm * 128 + row;
      *(bhalf8*)(C + (size_t)m_g * HD + bn * 128 + ck) = v;
    }
  }
}

// ---------- 4) fused kv / softmax(axis=i) / pooled, per chunk ----------
__global__ __launch_bounds__(256)
void pool_softmax(const short* __restrict__ QT, const short* __restrict__ KT,
                  const short* __restrict__ V, float* __restrict__ pooled, int b0) {
  const int t    = threadIdx.x;
  const int lane = t & 63;
  const int wave = t >> 6;
  const int task = blockIdx.x * 4 + wave;
  const int j  = task & 1023;
  const int bh = task >> 10;
  const int bl = bh >> 3, h = bh & 7;
  const size_t n = (size_t)h * 1024 + j;

  const bhalf8* qp = (const bhalf8*)(QT + ((size_t)bl * HD + n) * 1024);
  const bhalf8* kp = (const bhalf8*)(KT + ((size_t)bl * HD + n) * 1024);
  const bhalf8* vp = (const bhalf8*)(V + ((size_t)bl * 1024 + j) * HD + (size_t)h * 1024);

  bhalf8 q0 = qp[lane], q1 = qp[64 + lane];
  bhalf8 k0 = kp[lane], k1 = kp[64 + lane];
  bhalf8 v0 = vp[lane], v1 = vp[64 + lane];

  float q[16], x[16];
  float m = -1e30f;
  #pragma unroll
  for (int e = 0; e < 8; ++e) {
    q[e]     = bf2f(q0[e]);  q[8 + e] = bf2f(q1[e]);
    x[e]     = bf2f(k0[e]) * bf2f(v0[e]) * 0.03125f;
    x[8 + e] = bf2f(k1[e]) * bf2f(v1[e]) * 0.03125f;
  }
  #pragma unroll
  for (int e = 0; e < 16; ++e) m = fmaxf(m, x[e]);
  #pragma unroll
  for (int off = 32; off; off >>= 1) m = fmaxf(m, __shfl_xor(m, off, 64));
  float se = 0.f, sq = 0.f;
  #pragma unroll
  for (int e = 0; e < 16; ++e) { float ex = __expf(x[e] - m); se += ex; sq += ex * q[e]; }
  #pragma unroll
  for (int off = 32; off; off >>= 1) { se += __shfl_xor(se, off, 64); sq += __shfl_xor(sq, off, 64); }
  if (lane == 0) pooled[((size_t)(b0 * 8) + bh) * 1024 + j] = sq / se;
}

// ---------- 5) out = pooled @ WL + bL, k-split x4 + reduce ----------
__global__ __launch_bounds__(256)
void final_gemm2(const float* __restrict__ pooled, const float* __restrict__ WL,
                 float* __restrict__ part) {
  __shared__ float sp[256][8];
  const int t  = threadIdx.x;
  const int bn = blockIdx.x;   // 32
  const int mg = blockIdx.y;   // 8
  const int kc = blockIdx.z;   // 4
  for (int idx = t; idx < 2048; idx += 256) {
    int mm = idx >> 8, k = idx & 255;
    sp[k][mm] = pooled[(size_t)(mg * 8 + mm) * 1024 + kc * 256 + k];
  }
  __syncthreads();
  const int n = bn * 256 + t;
  float acc[8];
  #pragma unroll
  for (int mm = 0; mm < 8; ++mm) acc[mm] = 0.f;
  const float* wp = WL + (size_t)(kc * 256) * HD + n;
  #pragma unroll 1
  for (int k0 = 0; k0 < 256; k0 += 8) {
    float wv[8];
    #pragma unroll
    for (int u = 0; u < 8; ++u) wv[u] = wp[(size_t)(k0 + u) * HD];
    #pragma unroll
    for (int u = 0; u < 8; ++u)
      #pragma unroll
      for (int mm = 0; mm < 8; ++mm) acc[mm] = fmaf(sp[k0 + u][mm], wv[u], acc[mm]);
  }
  #pragma unroll
  for (int mm = 0; mm < 8; ++mm)
    part[((size_t)kc * 64 + mg * 8 + mm) * HD + n] = acc[mm];
}

__global__ __launch_bounds__(256)
void final_reduce(const float* __restrict__ part, const float* __restrict__ bL,
                  float* __restrict__ out) {
  int id = blockIdx.x * 256 + threadIdx.x;        // 131072 f32x4 groups
  const f32x4* p4 = (const f32x4*)part;
  f32x4 s = p4[id];
  s = s + p4[131072 + id];
  s = s + p4[262144 + id];
  s = s + p4[393216 + id];
  f32x4 bb = ((const f32x4*)bL)[id & 2047];
  ((f32x4*)out)[id] = s + bb;
}

// ---------- launch ----------
extern "C" void kernel_launch(void* const* d_in, const int* in_sizes, int n_in,
                              void* d_out, int out_size, void* d_ws, size_t ws_size,
                              hipStream_t stream) {
  const float* inputs = (const float*)d_in[0];
  const float* Wq = (const float*)d_in[1];
  const float* bq = (const float*)d_in[2];
  const float* Wk = (const float*)d_in[3];
  const float* bk = (const float*)d_in[4];
  const float* Wv = (const float*)d_in[5];
  const float* bv = (const float*)d_in[6];
  const float* WL = (const float*)d_in[7];
  const float* bL = (const float*)d_in[8];
  float* out = (float*)d_out;

  const size_t MB = 1ull << 20;
  int CB; bool threeW;
  if      (ws_size >= 449 * MB) { CB = 8; threeW = true;  }
  else if (ws_size >= 249 * MB) { CB = 4; threeW = true;  }
  else if (ws_size >= 149 * MB) { CB = 2; threeW = true;  }
  else if (ws_size >=  99 * MB) { CB = 1; threeW = true;  }
  else                          { CB = 1; threeW = false; }

  char* ws = (char*)d_ws;
  short* WT0 = (short*)ws;
  short* WT1 = threeW ? (short*)(ws + 16 * MB) : WT0;
  short* WT2 = threeW ? (short*)(ws + 32 * MB) : WT0;
  char* pp = ws + (threeW ? 48 : 16) * MB;
  short* Abf = (short*)pp;  pp += (size_t)CB * 2  * MB;
  short* QT  = (short*)pp;  pp += (size_t)CB * 16 * MB;
  short* KT  = (short*)pp;  pp += (size_t)CB * 16 * MB;
  short* Vn  = (short*)pp;  pp += (size_t)CB * 16 * MB;
  float* pooled = (float*)pp;
  float* part = (float*)QT;      // 8 MB partials; QT free when final runs

  const float* Wmat[3] = {Wq, Wk, Wv};
  const float* bvec[3] = {bq, bk, bv};
  short*       WTs[3]  = {WT0, WT1, WT2};
  short*       Cout[3] = {QT, KT, Vn};

  dim3 tg(16, 128);
  if (threeW)
    for (int pj = 0; pj < 3; ++pj)
      transpose_w<<<tg, 256, 0, stream>>>(Wmat[pj], WTs[pj]);

  for (int b0 = 0; b0 < 8; b0 += CB) {
    cvt_f32_bf16<<<CB * 512, 256, 0, stream>>>(inputs + ((size_t)b0 << 20), Abf, CB << 17);
    for (int pj = 0; pj < 3; ++pj) {
      if (!threeW)
        transpose_w<<<tg, 256, 0, stream>>>(Wmat[pj], WT0);
      if (pj < 2)
        gemm_proj<true ><<<CB * 512, 256, 0, stream>>>(Abf, WTs[pj], bvec[pj], Cout[pj]);
      else
        gemm_proj<false><<<CB * 512, 256, 0, stream>>>(Abf, WTs[pj], bvec[pj], Cout[pj]);
    }
    pool_softmax<<<CB * 2048, 256, 0, stream>>>(QT, KT, Vn, pooled, b0);
  }
  final_gemm2<<<dim3(32, 8, 4), 256, 0, stream>>>(pooled, WL, part);
  final_reduce<<<512, 256, 0, stream>>>(part, bL, out);
}

// Round 10
// 530.007 us; speedup vs baseline: 1.1025x; 1.0031x over previous
//
#include <hip/hip_runtime.h>
#include <hip/hip_bf16.h>
#include <stdint.h>

// ---------- types ----------
typedef __attribute__((ext_vector_type(4))) float  f32x4;
typedef __attribute__((ext_vector_type(4))) float  fvec4;
typedef __attribute__((ext_vector_type(8))) short  bhalf8;   // 8 bf16 (raw bits)
typedef __attribute__((ext_vector_type(4))) short  bhalf4;

typedef const __attribute__((address_space(1))) void glb_void;
typedef __attribute__((address_space(3))) void lds_void;

#define HD 8192
#define KDIM 1024

__device__ __forceinline__ float bf2f(short s) {
  union { float f; uint32_t u; } cv; cv.u = ((uint32_t)(uint16_t)s) << 16; return cv.f;
}
__device__ __forceinline__ short f2bf(float f) {
  union { float f; uint32_t u; } cv; cv.f = f;
  uint32_t u = cv.u;
  uint32_t r = (u + 0x7FFFu + ((u >> 16) & 1u)) >> 16;  // RNE
  return (short)(uint16_t)r;
}

// ---------- 1) f32 -> bf16 convert ----------
__global__ void cvt_f32_bf16(const float* __restrict__ in, short* __restrict__ out, int n8) {
  int idx = blockIdx.x * blockDim.x + threadIdx.x;
  if (idx >= n8) return;
  fvec4 a = ((const fvec4*)in)[idx * 2 + 0];
  fvec4 b = ((const fvec4*)in)[idx * 2 + 1];
  bhalf8 o;
  o[0]=f2bf(a[0]); o[1]=f2bf(a[1]); o[2]=f2bf(a[2]); o[3]=f2bf(a[3]);
  o[4]=f2bf(b[0]); o[5]=f2bf(b[1]); o[6]=f2bf(b[2]); o[7]=f2bf(b[3]);
  ((bhalf8*)out)[idx] = o;
}

// ---------- 2) W[1024][8192] f32 -> WT[8192][1024] bf16 ----------
__global__ __launch_bounds__(256)
void transpose_w(const float* __restrict__ W, short* __restrict__ WT) {
  __shared__ float tile[64][65];
  const int bk = blockIdx.x;   // 16
  const int bn = blockIdx.y;   // 128
  const int t  = threadIdx.x;
  #pragma unroll
  for (int p = 0; p < 4; ++p) {
    int r = p * 16 + (t >> 4);
    int c = (t & 15) * 4;
    fvec4 v = *(const fvec4*)(W + (size_t)(bk * 64 + r) * HD + bn * 64 + c);
    tile[r][c+0] = v[0]; tile[r][c+1] = v[1]; tile[r][c+2] = v[2]; tile[r][c+3] = v[3];
  }
  __syncthreads();
  #pragma unroll
  for (int p = 0; p < 2; ++p) {
    int rr = p * 32 + (t >> 3);
    int cc = (t & 7) * 8;
    bhalf8 o;
    #pragma unroll
    for (int e = 0; e < 8; ++e) o[e] = f2bf(tile[cc + e][rr]);
    *(bhalf8*)(WT + (size_t)(bn * 64 + rr) * KDIM + bk * 64 + cc) = o;
  }
}

// ---------- 3) 128x128 GEMM (R5/R8-verified best: ~1018 TF) ----------
// A:[M][1024] bf16, BT:[8192][1024] bf16.
// TRANSPOSED: CT[b_l][n][i] (b_l = m/1024, i = m%1024); else C[m][8192].
template <bool TRANSPOSED>
__global__ __launch_bounds__(256, 2)
void gemm_proj(const short* __restrict__ A, const short* __restrict__ BT,
               const float* __restrict__ bias, short* __restrict__ C) {
  constexpr int LDC = 136;                 // bf16 elems; 272B row stride
  __shared__ alignas(16) short smem2[128 * LDC];   // 34816 B: As+Bs, then Cs
  short* As = smem2;
  short* Bs = smem2 + 8192;
  short* Cs = smem2;

  const int t    = threadIdx.x;
  const int lane = t & 63;
  const int wave = t >> 6;
  const int bm   = blockIdx.x >> 6;
  const int bn   = blockIdx.x & 63;
  const int wr   = wave >> 1, wc = wave & 1;

  f32x4 acc[4][4];
  #pragma unroll
  for (int i = 0; i < 4; ++i)
    #pragma unroll
    for (int j = 0; j < 4; ++j) acc[i][j] = (f32x4)(0.f);

  // staging: lane covers row (c*8 + lane>>3), LDS slot (lane&7); global slot
  // pre-swizzled: gslot = (lane&7) ^ (row&7)   [rule #21: linear LDS dest]
  const int gslot = ((lane & 7) ^ (lane >> 3)) * 8;
  const short* aRow = A  + (size_t)(bm * 128 + (lane >> 3)) * KDIM + gslot;
  const short* bRow = BT + (size_t)(bn * 128 + (lane >> 3)) * KDIM + gslot;

  const int arow = wr * 64 + (lane & 15);
  const int brow = wc * 64 + (lane & 15);
  const int kbase = (lane >> 4) * 8;       // pre-XOR k elem offset within row
  const int swz  = (lane & 7) * 8;         // read-side XOR (row&7 == lane&7)

  for (int kt = 0; kt < 16; ++kt) {
    __syncthreads();
    #pragma unroll
    for (int s = 0; s < 4; ++s) {
      int c = s * 4 + wave;
      __builtin_amdgcn_global_load_lds(
          (glb_void*)(aRow + (size_t)(c * 8) * KDIM + kt * 64),
          (lds_void*)((char*)As + c * 1024), 16, 0, 0);
      __builtin_amdgcn_global_load_lds(
          (glb_void*)(bRow + (size_t)(c * 8) * KDIM + kt * 64),
          (lds_void*)((char*)Bs + c * 1024), 16, 0, 0);
    }
    __syncthreads();
    #pragma unroll
    for (int kk = 0; kk < 2; ++kk) {
      bhalf8 af[4], bfm[4];
      #pragma unroll
      for (int mi = 0; mi < 4; ++mi)
        af[mi] = *(const bhalf8*)(As + (arow + mi * 16) * 64 + ((kk * 32 + kbase) ^ swz));
      #pragma unroll
      for (int ni = 0; ni < 4; ++ni)
        bfm[ni] = *(const bhalf8*)(Bs + (brow + ni * 16) * 64 + ((kk * 32 + kbase) ^ swz));
      #pragma unroll
      for (int mi = 0; mi < 4; ++mi)
        #pragma unroll
        for (int ni = 0; ni < 4; ++ni)
          acc[mi][ni] = __builtin_amdgcn_mfma_f32_16x16x32_bf16(af[mi], bfm[ni], acc[mi][ni], 0, 0, 0);
    }
  }

  __syncthreads();   // all frag reads done; reuse smem as Cs

  float bv4[4];
  #pragma unroll
  for (int ni = 0; ni < 4; ++ni) bv4[ni] = bias[bn * 128 + wc * 64 + ni * 16 + (lane & 15)];

  #pragma unroll
  for (int mi = 0; mi < 4; ++mi) {
    #pragma unroll
    for (int ni = 0; ni < 4; ++ni) {
      const int r0 = wr * 64 + mi * 16 + (lane >> 4) * 4;   // m_local
      const int cl = wc * 64 + ni * 16 + (lane & 15);       // n_local
      if (TRANSPOSED) {
        bhalf4 pk;
        #pragma unroll
        for (int e = 0; e < 4; ++e) pk[e] = f2bf(acc[mi][ni][e] + bv4[ni]);
        *(bhalf4*)(Cs + cl * LDC + r0) = pk;           // Cs[n_local][m_local]
      } else {
        #pragma unroll
        for (int e = 0; e < 4; ++e) Cs[(r0 + e) * LDC + cl] = f2bf(acc[mi][ni][e] + bv4[ni]);
      }
    }
  }
  __syncthreads();

  #pragma unroll
  for (int p = 0; p < 8; ++p) {
    const int row = p * 16 + (t >> 4);
    const int ck  = (t & 15) * 8;
    bhalf8 v = *(const bhalf8*)(Cs + row * LDC + ck);
    if (TRANSPOSED) {
      const int n_g   = bn * 128 + row;
      const int mbase = bm * 128;
      const int bl    = mbase >> 10;                  // chunk-local batch
      const int ib    = (mbase & 1023) + ck;
      *(bhalf8*)(C + ((size_t)bl * HD + n_g) * 1024 + ib) = v;
    } else {
      const int m_g = bm * 128 + row;
      *(bhalf8*)(C + (size_t)m_g * HD + bn * 128 + ck) = v;
    }
  }
}

// ---------- 4) fused kv / softmax(axis=i) / pooled, per chunk ----------
__global__ __launch_bounds__(256)
void pool_softmax(const short* __restrict__ QT, const short* __restrict__ KT,
                  const short* __restrict__ V, float* __restrict__ pooled, int b0) {
  const int t    = threadIdx.x;
  const int lane = t & 63;
  const int wave = t >> 6;
  const int task = blockIdx.x * 4 + wave;
  const int j  = task & 1023;
  const int bh = task >> 10;
  const int bl = bh >> 3, h = bh & 7;
  const size_t n = (size_t)h * 1024 + j;

  const bhalf8* qp = (const bhalf8*)(QT + ((size_t)bl * HD + n) * 1024);
  const bhalf8* kp = (const bhalf8*)(KT + ((size_t)bl * HD + n) * 1024);
  const bhalf8* vp = (const bhalf8*)(V + ((size_t)bl * 1024 + j) * HD + (size_t)h * 1024);

  bhalf8 q0 = qp[lane], q1 = qp[64 + lane];
  bhalf8 k0 = kp[lane], k1 = kp[64 + lane];
  bhalf8 v0 = vp[lane], v1 = vp[64 + lane];

  float q[16], x[16];
  float m = -1e30f;
  #pragma unroll
  for (int e = 0; e < 8; ++e) {
    q[e]     = bf2f(q0[e]);  q[8 + e] = bf2f(q1[e]);
    x[e]     = bf2f(k0[e]) * bf2f(v0[e]) * 0.03125f;
    x[8 + e] = bf2f(k1[e]) * bf2f(v1[e]) * 0.03125f;
  }
  #pragma unroll
  for (int e = 0; e < 16; ++e) m = fmaxf(m, x[e]);
  #pragma unroll
  for (int off = 32; off; off >>= 1) m = fmaxf(m, __shfl_xor(m, off, 64));
  float se = 0.f, sq = 0.f;
  #pragma unroll
  for (int e = 0; e < 16; ++e) { float ex = __expf(x[e] - m); se += ex; sq += ex * q[e]; }
  #pragma unroll
  for (int off = 32; off; off >>= 1) { se += __shfl_xor(se, off, 64); sq += __shfl_xor(sq, off, 64); }
  if (lane == 0) pooled[((size_t)(b0 * 8) + bh) * 1024 + j] = sq / se;
}

// ---------- 5) out = pooled @ WL + bL, k-split x4 + reduce ----------
__global__ __launch_bounds__(256)
void final_gemm2(const float* __restrict__ pooled, const float* __restrict__ WL,
                 float* __restrict__ part) {
  __shared__ float sp[256][8];
  const int t  = threadIdx.x;
  const int bn = blockIdx.x;   // 32
  const int mg = blockIdx.y;   // 8
  const int kc = blockIdx.z;   // 4
  for (int idx = t; idx < 2048; idx += 256) {
    int mm = idx >> 8, k = idx & 255;
    sp[k][mm] = pooled[(size_t)(mg * 8 + mm) * 1024 + kc * 256 + k];
  }
  __syncthreads();
  const int n = bn * 256 + t;
  float acc[8];
  #pragma unroll
  for (int mm = 0; mm < 8; ++mm) acc[mm] = 0.f;
  const float* wp = WL + (size_t)(kc * 256) * HD + n;
  #pragma unroll 1
  for (int k0 = 0; k0 < 256; k0 += 8) {
    float wv[8];
    #pragma unroll
    for (int u = 0; u < 8; ++u) wv[u] = wp[(size_t)(k0 + u) * HD];
    #pragma unroll
    for (int u = 0; u < 8; ++u)
      #pragma unroll
      for (int mm = 0; mm < 8; ++mm) acc[mm] = fmaf(sp[k0 + u][mm], wv[u], acc[mm]);
  }
  #pragma unroll
  for (int mm = 0; mm < 8; ++mm)
    part[((size_t)kc * 64 + mg * 8 + mm) * HD + n] = acc[mm];
}

__global__ __launch_bounds__(256)
void final_reduce(const float* __restrict__ part, const float* __restrict__ bL,
                  float* __restrict__ out) {
  int id = blockIdx.x * 256 + threadIdx.x;        // 131072 f32x4 groups
  const f32x4* p4 = (const f32x4*)part;
  f32x4 s = p4[id];
  s = s + p4[131072 + id];
  s = s + p4[262144 + id];
  s = s + p4[393216 + id];
  f32x4 bb = ((const f32x4*)bL)[id & 2047];
  ((f32x4*)out)[id] = s + bb;
}

// ---------- launch ----------
extern "C" void kernel_launch(void* const* d_in, const int* in_sizes, int n_in,
                              void* d_out, int out_size, void* d_ws, size_t ws_size,
                              hipStream_t stream) {
  const float* inputs = (const float*)d_in[0];
  const float* Wq = (const float*)d_in[1];
  const float* bq = (const float*)d_in[2];
  const float* Wk = (const float*)d_in[3];
  const float* bk = (const float*)d_in[4];
  const float* Wv = (const float*)d_in[5];
  const float* bv = (const float*)d_in[6];
  const float* WL = (const float*)d_in[7];
  const float* bL = (const float*)d_in[8];
  float* out = (float*)d_out;

  const size_t MB = 1ull << 20;
  int CB; bool threeW;
  if      (ws_size >= 449 * MB) { CB = 8; threeW = true;  }
  else if (ws_size >= 249 * MB) { CB = 4; threeW = true;  }
  else if (ws_size >= 149 * MB) { CB = 2; threeW = true;  }
  else if (ws_size >=  99 * MB) { CB = 1; threeW = true;  }
  else                          { CB = 1; threeW = false; }

  char* ws = (char*)d_ws;
  short* WT0 = (short*)ws;
  short* WT1 = threeW ? (short*)(ws + 16 * MB) : WT0;
  short* WT2 = threeW ? (short*)(ws + 32 * MB) : WT0;
  char* pp = ws + (threeW ? 48 : 16) * MB;
  short* Abf = (short*)pp;  pp += (size_t)CB * 2  * MB;
  short* QT  = (short*)pp;  pp += (size_t)CB * 16 * MB;
  short* KT  = (short*)pp;  pp += (size_t)CB * 16 * MB;
  short* Vn  = (short*)pp;  pp += (size_t)CB * 16 * MB;
  float* pooled = (float*)pp;
  float* part = (float*)QT;      // 8 MB partials; QT free when final runs

  const float* Wmat[3] = {Wq, Wk, Wv};
  const float* bvec[3] = {bq, bk, bv};
  short*       WTs[3]  = {WT0, WT1, WT2};
  short*       Cout[3] = {QT, KT, Vn};

  dim3 tg(16, 128);
  if (threeW)
    for (int pj = 0; pj < 3; ++pj)
      transpose_w<<<tg, 256, 0, stream>>>(Wmat[pj], WTs[pj]);

  for (int b0 = 0; b0 < 8; b0 += CB) {
    cvt_f32_bf16<<<CB * 512, 256, 0, stream>>>(inputs + ((size_t)b0 << 20), Abf, CB << 17);
    for (int pj = 0; pj < 3; ++pj) {
      if (!threeW)
        transpose_w<<<tg, 256, 0, stream>>>(Wmat[pj], WT0);
      if (pj < 2)
        gemm_proj<true ><<<CB * 512, 256, 0, stream>>>(Abf, WTs[pj], bvec[pj], Cout[pj]);
      else
        gemm_proj<false><<<CB * 512, 256, 0, stream>>>(Abf, WTs[pj], bvec[pj], Cout[pj]);
    }
    pool_softmax<<<CB * 2048, 256, 0, stream>>>(QT, KT, Vn, pooled, b0);
  }
  final_gemm2<<<dim3(32, 8, 4), 256, 0, stream>>>(pooled, WL, part);
  final_reduce<<<512, 256, 0, stream>>>(part, bL, out);
}